// Round 1
// baseline (316.472 us; speedup 1.0000x reference)
//
#include <hip/hip_runtime.h>

typedef __attribute__((ext_vector_type(8))) short short8;
typedef __attribute__((ext_vector_type(4))) float f32x4;
typedef __attribute__((ext_vector_type(4))) short short4v;

__device__ __forceinline__ short f2bs(float f) {
    union { float f; unsigned u; } c; c.f = f;
    unsigned r = 0x7FFFu + ((c.u >> 16) & 1u);
    return (short)((c.u + r) >> 16);
}

__device__ __forceinline__ void gld_lds16(const void* g, void* l) {
    __builtin_amdgcn_global_load_lds(
        (const __attribute__((address_space(1))) unsigned int*)g,
        (__attribute__((address_space(3))) unsigned int*)l, 16, 0, 0);
}

__device__ __forceinline__ f32x4 mfma16(short8 a, short8 b, f32x4 c) {
    return __builtin_amdgcn_mfma_f32_16x16x32_bf16(a, b, c, 0, 0, 0);
}

// ---------------- conversion: fp32 -> bf16 (vectorized x4) ----------------
__global__ __launch_bounds__(256) void cvt_kernel(const float* __restrict__ src,
                                                  short* __restrict__ dst, int n4)
{
    int i = blockIdx.x * 256 + threadIdx.x;
    if (i >= n4) return;
    float4 v = ((const float4*)src)[i];
    short4v o;
    o.x = f2bs(v.x); o.y = f2bs(v.y); o.z = f2bs(v.z); o.w = f2bs(v.w);
    ((short4v*)dst)[i] = o;
}

// ---------------- GEMM: C = A @ B^T (B stored [N][K] row-major) ----------------
// m97 structure: 128x128 tile, BK=32, 4 waves (2x2), global_load_lds width 16.
// MODE 0: QKV — bias add + scatter to per-head [b,h,s,d] bf16.
// MODE 1: O-proj — + bo + residual x, write fp32.
#define BM 128
#define BN 128
#define BK 32

template<int MODE>
__global__ __launch_bounds__(256) void gemm_bt(
    const short* __restrict__ A, const short* __restrict__ B,
    int M, int N, int K,
    const float* __restrict__ b0, const float* __restrict__ b1, const float* __restrict__ b2,
    short* __restrict__ oq, short* __restrict__ ok_, short* __restrict__ ov,
    const float* __restrict__ bo, const float* __restrict__ xres,
    float* __restrict__ outf)
{
    __shared__ __align__(16) short As[BM * BK];
    __shared__ __align__(16) short Bs[BN * BK];
    const int tid = threadIdx.x;
    const int wave = tid >> 6, lane = tid & 63;
    const int lhi = lane >> 4, llo = lane & 15;
    const int row0 = blockIdx.x * BM, col0 = blockIdx.y * BN;
    const int wr = (wave >> 1) * 64, wc = (wave & 1) * 64;

    f32x4 acc[4][4] = {};

    // staging chunk (16B) assignment: chunk c -> row c>>2, kchunk c&3
    const int c0 = tid, c1 = 256 + tid;
    const short* gA0 = A + (size_t)(row0 + (c0 >> 2)) * K + (c0 & 3) * 8;
    const short* gA1 = A + (size_t)(row0 + (c1 >> 2)) * K + (c1 & 3) * 8;
    const short* gB0 = B + (size_t)(col0 + (c0 >> 2)) * K + (c0 & 3) * 8;
    const short* gB1 = B + (size_t)(col0 + (c1 >> 2)) * K + (c1 & 3) * 8;
    short* lA0 = &As[(size_t)(wave * 64) * 8];
    short* lA1 = &As[(size_t)(256 + wave * 64) * 8];
    short* lB0 = &Bs[(size_t)(wave * 64) * 8];
    short* lB1 = &Bs[(size_t)(256 + wave * 64) * 8];

    for (int k0 = 0; k0 < K; k0 += BK) {
        gld_lds16(gA0 + k0, lA0);
        gld_lds16(gA1 + k0, lA1);
        gld_lds16(gB0 + k0, lB0);
        gld_lds16(gB1 + k0, lB1);
        __syncthreads();
        short8 af[4], bf[4];
        #pragma unroll
        for (int i = 0; i < 4; ++i) {
            af[i] = *(const short8*)&As[(wr + i * 16 + llo) * BK + lhi * 8];
            bf[i] = *(const short8*)&Bs[(wc + i * 16 + llo) * BK + lhi * 8];
        }
        #pragma unroll
        for (int i = 0; i < 4; ++i)
            #pragma unroll
            for (int j = 0; j < 4; ++j)
                acc[i][j] = mfma16(af[i], bf[j], acc[i][j]);
        __syncthreads();
    }

    // epilogue — C/D layout: col = lane&15, row = (lane>>4)*4 + reg
    #pragma unroll
    for (int i = 0; i < 4; ++i) {
        #pragma unroll
        for (int j = 0; j < 4; ++j) {
            #pragma unroll
            for (int r = 0; r < 4; ++r) {
                int m = row0 + wr + i * 16 + lhi * 4 + r;
                int n = col0 + wc + j * 16 + llo;
                float v = acc[i][j][r];
                if (MODE == 0) {
                    int which = n >> 10, nn = n & 1023;
                    const float* bia = which == 0 ? b0 : (which == 1 ? b1 : b2);
                    short* dst = which == 0 ? oq : (which == 1 ? ok_ : ov);
                    v += bia[nn];
                    int h = nn >> 6, d = nn & 63;
                    int bb = m >> 11, s = m & 2047;
                    dst[((size_t)((bb * 16 + h) * 2048 + s)) * 64 + d] = f2bs(v);
                } else {
                    size_t idx = (size_t)m * N + n;
                    outf[idx] = v + bo[n] + xres[idx];
                }
            }
        }
    }
}

// ---------------- flash attention (causal), per (b,h) ----------------
// block: 256 thr = 4 waves; each wave owns 16 q rows; KV tile = 32 rows.
#define QBLK 64
#define KBLK 32

__global__ __launch_bounds__(256) void attn_kernel(
    const short* __restrict__ Q, const short* __restrict__ K,
    const short* __restrict__ V, short* __restrict__ O)
{
    const int bh = blockIdx.y;            // b = bh>>4, h = bh&15
    const int q0 = blockIdx.x * QBLK;
    const short* Qb = Q + (size_t)bh * 2048 * 64;
    const short* Kb = K + (size_t)bh * 2048 * 64;
    const short* Vb = V + (size_t)bh * 2048 * 64;

    __shared__ __align__(16) short Ks[KBLK * 64];   // [kk][d]
    __shared__ __align__(16) short Vts[64 * KBLK];  // [d][kk]
    __shared__ __align__(16) short Ps[4][16 * KBLK];

    const int tid = threadIdx.x, wave = tid >> 6, lane = tid & 63;
    const int lhi = lane >> 4, llo = lane & 15;
    const int qw = q0 + wave * 16;

    // Q fragments (A operand): lane holds row llo, k = lhi*8..+8 (d-dim)
    short8 qf[2];
    #pragma unroll
    for (int i = 0; i < 2; ++i)
        qf[i] = *(const short8*)&Qb[(size_t)(qw + llo) * 64 + i * 32 + lhi * 8];

    f32x4 o[4] = {};
    float mrow[4], lrow[4];
    #pragma unroll
    for (int j = 0; j < 4; ++j) { mrow[j] = -1e30f; lrow[j] = 0.f; }

    const int ntiles = (q0 + QBLK) / KBLK;
    for (int kt = 0; kt < ntiles; ++kt) {
        const int kk0 = kt * KBLK;
        // stage K tile: 256 chunks of 16B, linear [kk][d]
        {
            const short* src = Kb + (size_t)(kk0 + (tid >> 3)) * 64 + (tid & 7) * 8;
            gld_lds16(src, &Ks[(size_t)wave * 512]);
        }
        // stage V^T: thread reads V[kk][d0..d0+8), writes transposed
        {
            int kk = tid >> 3, d0 = (tid & 7) * 8;
            short8 vv = *(const short8*)&Vb[(size_t)(kk0 + kk) * 64 + d0];
            #pragma unroll
            for (int i = 0; i < 8; ++i) Vts[(d0 + i) * KBLK + kk] = vv[i];
        }
        __syncthreads();

        // S = Q K^T (two 16x16 kk-tiles, chained over d)
        f32x4 st[2];
        #pragma unroll
        for (int t = 0; t < 2; ++t) {
            short8 kf0 = *(const short8*)&Ks[(t * 16 + llo) * 64 + lhi * 8];
            short8 kf1 = *(const short8*)&Ks[(t * 16 + llo) * 64 + 32 + lhi * 8];
            f32x4 s = {};
            s = mfma16(qf[0], kf0, s);
            s = mfma16(qf[1], kf1, s);
            st[t] = s;
        }

        // scale + causal max
        float tmax[4];
        #pragma unroll
        for (int j = 0; j < 4; ++j) {
            int qg = qw + lhi * 4 + j;
            float mx = -1e30f;
            #pragma unroll
            for (int t = 0; t < 2; ++t) {
                st[t][j] *= 0.125f;
                int kg = kk0 + t * 16 + llo;
                mx = (kg <= qg) ? fmaxf(mx, st[t][j]) : mx;
            }
            #pragma unroll
            for (int d = 1; d < 16; d <<= 1) mx = fmaxf(mx, __shfl_xor(mx, d));
            tmax[j] = mx;
        }

        float alpha[4];
        #pragma unroll
        for (int j = 0; j < 4; ++j) {
            float mnew = fmaxf(mrow[j], tmax[j]);
            alpha[j] = __expf(mrow[j] - mnew);
            mrow[j] = mnew;
        }

        // P = exp(S - m), row sums, write P to per-wave LDS
        #pragma unroll
        for (int j = 0; j < 4; ++j) {
            int qg = qw + lhi * 4 + j;
            float rs = 0.f;
            #pragma unroll
            for (int t = 0; t < 2; ++t) {
                int kg = kk0 + t * 16 + llo;
                float p = (kg <= qg) ? __expf(st[t][j] - mrow[j]) : 0.f;
                rs += p;
                Ps[wave][(lhi * 4 + j) * KBLK + t * 16 + llo] = f2bs(p);
            }
            #pragma unroll
            for (int d = 1; d < 16; d <<= 1) rs += __shfl_xor(rs, d);
            lrow[j] = lrow[j] * alpha[j] + rs;
        }

        // rescale O
        #pragma unroll
        for (int dt = 0; dt < 4; ++dt)
            #pragma unroll
            for (int j = 0; j < 4; ++j) o[dt][j] *= alpha[j];

        // O += P @ V   (P: A operand from LDS; V^T: B operand)
        short8 pf = *(const short8*)&Ps[wave][llo * KBLK + lhi * 8];
        #pragma unroll
        for (int dt = 0; dt < 4; ++dt) {
            short8 vf = *(const short8*)&Vts[(dt * 16 + llo) * KBLK + lhi * 8];
            o[dt] = mfma16(pf, vf, o[dt]);
        }
        __syncthreads();
    }

    // finalize: divide by l, write to [4096][1024] (col = h*64+d)
    const int b = bh >> 4, h = bh & 15;
    #pragma unroll
    for (int j = 0; j < 4; ++j) {
        float inv = 1.f / lrow[j];
        int s = qw + lhi * 4 + j;
        size_t row = (size_t)(b * 2048 + s);
        #pragma unroll
        for (int dt = 0; dt < 4; ++dt) {
            int d = dt * 16 + llo;
            O[row * 1024 + h * 64 + d] = f2bs(o[dt][j] * inv);
        }
    }
}

// ---------------- in-place LayerNorm over rows of 1024 ----------------
__global__ __launch_bounds__(256) void ln_kernel(float* __restrict__ out,
        const float* __restrict__ gamma, const float* __restrict__ beta)
{
    const int row = blockIdx.x;
    float* p = out + (size_t)row * 1024;
    const int tid = threadIdx.x;
    float4 v = ((const float4*)p)[tid];
    float s = v.x + v.y + v.z + v.w;
    float ss = v.x * v.x + v.y * v.y + v.z * v.z + v.w * v.w;
    #pragma unroll
    for (int d = 1; d < 64; d <<= 1) {
        s  += __shfl_xor(s, d);
        ss += __shfl_xor(ss, d);
    }
    __shared__ float red[8];
    const int wave = tid >> 6, lane = tid & 63;
    if (lane == 0) { red[wave] = s; red[4 + wave] = ss; }
    __syncthreads();
    s  = red[0] + red[1] + red[2] + red[3];
    ss = red[4] + red[5] + red[6] + red[7];
    const float mu = s * (1.0f / 1024.0f);
    const float var = ss * (1.0f / 1024.0f) - mu * mu;
    const float rstd = rsqrtf(var + 1e-5f);
    float4 g = ((const float4*)gamma)[tid];
    float4 b = ((const float4*)beta)[tid];
    v.x = (v.x - mu) * rstd * g.x + b.x;
    v.y = (v.y - mu) * rstd * g.y + b.y;
    v.z = (v.z - mu) * rstd * g.z + b.z;
    v.w = (v.w - mu) * rstd * g.w + b.w;
    ((float4*)p)[tid] = v;
}

extern "C" void kernel_launch(void* const* d_in, const int* in_sizes, int n_in,
                              void* d_out, int out_size, void* d_ws, size_t ws_size,
                              hipStream_t stream)
{
    const float* x  = (const float*)d_in[0];
    const float* Wq = (const float*)d_in[1];
    const float* bq = (const float*)d_in[2];
    const float* Wk = (const float*)d_in[3];
    const float* bk = (const float*)d_in[4];
    const float* Wv = (const float*)d_in[5];
    const float* bv = (const float*)d_in[6];
    const float* Wo = (const float*)d_in[7];
    const float* bo = (const float*)d_in[8];
    const float* gamma = (const float*)d_in[9];
    const float* beta  = (const float*)d_in[10];
    float* out = (float*)d_out;

    char* ws = (char*)d_ws;
    short* xb   = (short*)(ws);                      // 4M elems (8 MB); reused as ab
    short* wqkv = (short*)(ws + (8ull  << 20));      // 3M (6 MB) [3072][1024]
    short* wob  = (short*)(ws + (14ull << 20));      // 1M (2 MB)
    short* qb   = (short*)(ws + (16ull << 20));      // [2][16][2048][64] bf16, 8 MB
    short* kb   = (short*)(ws + (24ull << 20));
    short* vb   = (short*)(ws + (32ull << 20));
    short* ab   = xb;                                // attn out [4096][1024]

    cvt_kernel<<<4096, 256, 0, stream>>>(x,  xb, 1048576);
    cvt_kernel<<<1024, 256, 0, stream>>>(Wq, wqkv,           262144);
    cvt_kernel<<<1024, 256, 0, stream>>>(Wk, wqkv + 1048576, 262144);
    cvt_kernel<<<1024, 256, 0, stream>>>(Wv, wqkv + 2097152, 262144);
    cvt_kernel<<<1024, 256, 0, stream>>>(Wo, wob, 262144);

    gemm_bt<0><<<dim3(32, 24), 256, 0, stream>>>(xb, wqkv, 4096, 3072, 1024,
        bq, bk, bv, qb, kb, vb, nullptr, nullptr, nullptr);

    attn_kernel<<<dim3(32, 32), 256, 0, stream>>>(qb, kb, vb, ab);

    gemm_bt<1><<<dim3(32, 8), 256, 0, stream>>>(ab, wob, 4096, 1024, 1024,
        nullptr, nullptr, nullptr, nullptr, nullptr, nullptr, bo, x, out);

    ln_kernel<<<4096, 256, 0, stream>>>(out, gamma, beta);
}

// Round 2
// 188.231 us; speedup vs baseline: 1.6813x; 1.6813x over previous
//
#include <hip/hip_runtime.h>

typedef __attribute__((ext_vector_type(8))) short short8;
typedef __attribute__((ext_vector_type(4))) float f32x4;
typedef __attribute__((ext_vector_type(4))) short short4v;

__device__ __forceinline__ short f2bs(float f) {
    union { float f; unsigned u; } c; c.f = f;
    unsigned r = 0x7FFFu + ((c.u >> 16) & 1u);
    return (short)((c.u + r) >> 16);
}

__device__ __forceinline__ void gld_lds16(const void* g, void* l) {
    __builtin_amdgcn_global_load_lds(
        (const __attribute__((address_space(1))) unsigned int*)g,
        (__attribute__((address_space(3))) unsigned int*)l, 16, 0, 0);
}

__device__ __forceinline__ f32x4 mfma16(short8 a, short8 b, f32x4 c) {
    return __builtin_amdgcn_mfma_f32_16x16x32_bf16(a, b, c, 0, 0, 0);
}

// ---------------- conversion: fp32 -> bf16 (vectorized x4) ----------------
__global__ __launch_bounds__(256) void cvt_kernel(const float* __restrict__ src,
                                                  short* __restrict__ dst, int n4)
{
    int i = blockIdx.x * 256 + threadIdx.x;
    if (i >= n4) return;
    float4 v = ((const float4*)src)[i];
    short4v o;
    o.x = f2bs(v.x); o.y = f2bs(v.y); o.z = f2bs(v.z); o.w = f2bs(v.w);
    ((short4v*)dst)[i] = o;
}

// ---------------- GEMM: C = A @ B^T (B stored [N][K] row-major) ----------------
// MODE 0: QKV — bias add; Q,K scatter to [b,h,s,d]; V scatter TRANSPOSED to [b,h,d,s].
// MODE 1: O-proj — + bo + residual x, write fp32.
#define BM 128
#define BN 128
#define BK 32

template<int MODE>
__global__ __launch_bounds__(256) void gemm_bt(
    const short* __restrict__ A, const short* __restrict__ B,
    int M, int N, int K,
    const float* __restrict__ b0, const float* __restrict__ b1, const float* __restrict__ b2,
    short* __restrict__ oq, short* __restrict__ ok_, short* __restrict__ ov,
    const float* __restrict__ bo, const float* __restrict__ xres,
    float* __restrict__ outf)
{
    __shared__ __align__(16) short As[BM * BK];
    __shared__ __align__(16) short Bs[BN * BK];
    const int tid = threadIdx.x;
    const int wave = tid >> 6, lane = tid & 63;
    const int lhi = lane >> 4, llo = lane & 15;
    const int row0 = blockIdx.x * BM, col0 = blockIdx.y * BN;
    const int wr = (wave >> 1) * 64, wc = (wave & 1) * 64;

    f32x4 acc[4][4] = {};

    const int c0 = tid, c1 = 256 + tid;
    const short* gA0 = A + (size_t)(row0 + (c0 >> 2)) * K + (c0 & 3) * 8;
    const short* gA1 = A + (size_t)(row0 + (c1 >> 2)) * K + (c1 & 3) * 8;
    const short* gB0 = B + (size_t)(col0 + (c0 >> 2)) * K + (c0 & 3) * 8;
    const short* gB1 = B + (size_t)(col0 + (c1 >> 2)) * K + (c1 & 3) * 8;
    short* lA0 = &As[(size_t)(wave * 64) * 8];
    short* lA1 = &As[(size_t)(256 + wave * 64) * 8];
    short* lB0 = &Bs[(size_t)(wave * 64) * 8];
    short* lB1 = &Bs[(size_t)(256 + wave * 64) * 8];

    for (int k0 = 0; k0 < K; k0 += BK) {
        gld_lds16(gA0 + k0, lA0);
        gld_lds16(gA1 + k0, lA1);
        gld_lds16(gB0 + k0, lB0);
        gld_lds16(gB1 + k0, lB1);
        __syncthreads();
        short8 af[4], bf[4];
        #pragma unroll
        for (int i = 0; i < 4; ++i) {
            af[i] = *(const short8*)&As[(wr + i * 16 + llo) * BK + lhi * 8];
            bf[i] = *(const short8*)&Bs[(wc + i * 16 + llo) * BK + lhi * 8];
        }
        #pragma unroll
        for (int i = 0; i < 4; ++i)
            #pragma unroll
            for (int j = 0; j < 4; ++j)
                acc[i][j] = mfma16(af[i], bf[j], acc[i][j]);
        __syncthreads();
    }

    // epilogue — C/D layout: col = lane&15, row = (lane>>4)*4 + reg
    #pragma unroll
    for (int i = 0; i < 4; ++i) {
        #pragma unroll
        for (int j = 0; j < 4; ++j) {
            #pragma unroll
            for (int r = 0; r < 4; ++r) {
                int m = row0 + wr + i * 16 + lhi * 4 + r;
                int n = col0 + wc + j * 16 + llo;
                float v = acc[i][j][r];
                if (MODE == 0) {
                    int which = n >> 10, nn = n & 1023;
                    const float* bia = which == 0 ? b0 : (which == 1 ? b1 : b2);
                    v += bia[nn];
                    int h = nn >> 6, d = nn & 63;
                    int bb = m >> 11, s = m & 2047;
                    short val = f2bs(v);
                    if (which == 2)
                        ov[((size_t)((bb * 16 + h) * 64 + d)) * 2048 + s] = val;
                    else {
                        short* dst = which == 0 ? oq : ok_;
                        dst[((size_t)((bb * 16 + h) * 2048 + s)) * 64 + d] = val;
                    }
                } else {
                    size_t idx = (size_t)m * N + n;
                    outf[idx] = v + bo[n] + xres[idx];
                }
            }
        }
    }
}

// ---------------- flash attention (causal), per (b,h) ----------------
// 4 waves x 16 q-rows = 64 q / block; KV tile = 64; K & V^T double-buffered,
// XOR-swizzled LDS staged via global_load_lds with pre-swizzled global src.
#define SCL 0.18033688011f   /* (1/8) * log2(e) */

__global__ __launch_bounds__(256) void attn_kernel(
    const short* __restrict__ Q, const short* __restrict__ K,
    const short* __restrict__ Vt, short* __restrict__ O)
{
    const int id = blockIdx.x;                 // 1024 blocks
    const int bh = (id & 7) * 4 + ((id >> 3) >> 5);   // XCD-grouped bh
    const int qt = 31 - ((id >> 3) & 31);             // heavy q-tiles first
    const int q0 = qt * 64;

    const short* Qb = Q  + (size_t)bh * 2048 * 64;
    const short* Kb = K  + (size_t)bh * 2048 * 64;
    const short* Vb = Vt + (size_t)bh * 64 * 2048;

    __shared__ __align__(16) short Ks[2][64 * 64];
    __shared__ __align__(16) short Vs[2][64 * 64];
    __shared__ __align__(16) short Ps[4][16 * 68];

    const int tid = threadIdx.x, wave = tid >> 6, lane = tid & 63;
    const int lhi = lane >> 4, llo = lane & 15;
    const int qw = q0 + wave * 16;

    // Q fragments (A operand), hoisted
    const short8 qf0 = *(const short8*)&Qb[(size_t)(qw + llo) * 64 + lhi * 8];
    const short8 qf1 = *(const short8*)&Qb[(size_t)(qw + llo) * 64 + 32 + lhi * 8];

    // staging: 512 granules of 16B per tile per array; thread -> granules tid, 256+tid.
    // LDS linear dest; global source col-granule pre-XORed so swizzled reads see K[row][col].
    const int tr = tid >> 3, tc = tid & 7, sc = tc ^ (tr & 7);
    const short* kS0 = Kb + (size_t)tr * 64 + sc * 8;
    const short* kS1 = Kb + (size_t)(32 + tr) * 64 + sc * 8;
    const short* vS0 = Vb + (size_t)tr * 2048 + sc * 8;
    const short* vS1 = Vb + (size_t)(32 + tr) * 2048 + sc * 8;
    const int dOff = wave * 512;

    f32x4 o[4] = {};
    float mrow[4], lrow[4];
    #pragma unroll
    for (int j = 0; j < 4; ++j) { mrow[j] = -1e30f; lrow[j] = 0.f; }

    const int nt = q0 / 64 + 1;

    gld_lds16(kS0, Ks[0] + dOff);
    gld_lds16(kS1, Ks[0] + 2048 + dOff);
    gld_lds16(vS0, Vs[0] + dOff);
    gld_lds16(vS1, Vs[0] + 2048 + dOff);
    __syncthreads();

    int cur = 0;
    for (int kt = 0; kt < nt; ++kt) {
        const int kk0 = kt * 64;
        if (kt + 1 < nt) {                     // prefetch next tile into other buffer
            const int nk = kk0 + 64;
            gld_lds16(kS0 + (size_t)nk * 64, Ks[cur ^ 1] + dOff);
            gld_lds16(kS1 + (size_t)nk * 64, Ks[cur ^ 1] + 2048 + dOff);
            gld_lds16(vS0 + nk, Vs[cur ^ 1] + dOff);
            gld_lds16(vS1 + nk, Vs[cur ^ 1] + 2048 + dOff);
        }

        // ---- S = Q K^T over 4 kk-subtiles (swizzled reads) ----
        f32x4 st[4];
        #pragma unroll
        for (int t = 0; t < 4; ++t) {
            const int row = t * 16 + llo;
            const int sw = (row & 7) << 3;     // short-index XOR
            short8 kf0 = *(const short8*)&Ks[cur][row * 64 + ((lhi * 8) ^ sw)];
            short8 kf1 = *(const short8*)&Ks[cur][row * 64 + ((lhi * 8 + 32) ^ sw)];
            f32x4 s = {};
            s = mfma16(qf0, kf0, s);
            s = mfma16(qf1, kf1, s);
            st[t][0] = s[0] * SCL; st[t][1] = s[1] * SCL;
            st[t][2] = s[2] * SCL; st[t][3] = s[3] * SCL;
        }

        if (kt == nt - 1) {                    // diagonal tile: causal mask
            #pragma unroll
            for (int t = 0; t < 4; ++t) {
                const int kg = kk0 + t * 16 + llo;
                #pragma unroll
                for (int j = 0; j < 4; ++j)
                    if (kg > qw + lhi * 4 + j) st[t][j] = -1e30f;
            }
        }

        // ---- online softmax (base-2 domain) ----
        float alpha[4];
        #pragma unroll
        for (int j = 0; j < 4; ++j) {
            float mx = fmaxf(fmaxf(st[0][j], st[1][j]), fmaxf(st[2][j], st[3][j]));
            #pragma unroll
            for (int d = 1; d < 16; d <<= 1) mx = fmaxf(mx, __shfl_xor(mx, d));
            const float mnew = fmaxf(mrow[j], mx);
            alpha[j] = exp2f(mrow[j] - mnew);
            mrow[j] = mnew;
        }
        #pragma unroll
        for (int j = 0; j < 4; ++j) {
            float rs = 0.f;
            #pragma unroll
            for (int t = 0; t < 4; ++t) {
                float p = exp2f(st[t][j] - mrow[j]);
                rs += p;
                Ps[wave][(lhi * 4 + j) * 68 + t * 16 + llo] = f2bs(p);
            }
            #pragma unroll
            for (int d = 1; d < 16; d <<= 1) rs += __shfl_xor(rs, d);
            lrow[j] = lrow[j] * alpha[j] + rs;
        }
        #pragma unroll
        for (int dt = 0; dt < 4; ++dt)
            #pragma unroll
            for (int j = 0; j < 4; ++j) o[dt][j] *= alpha[j];

        // ---- O += P V (P from per-wave LDS; V^T swizzled reads) ----
        const short8 pf0 = *(const short8*)&Ps[wave][llo * 68 + lhi * 8];
        const short8 pf1 = *(const short8*)&Ps[wave][llo * 68 + 32 + lhi * 8];
        #pragma unroll
        for (int dt = 0; dt < 4; ++dt) {
            const int row = dt * 16 + llo;
            const int sw = (row & 7) << 3;
            short8 vf0 = *(const short8*)&Vs[cur][row * 64 + ((lhi * 8) ^ sw)];
            short8 vf1 = *(const short8*)&Vs[cur][row * 64 + ((lhi * 8 + 32) ^ sw)];
            o[dt] = mfma16(pf0, vf0, o[dt]);
            o[dt] = mfma16(pf1, vf1, o[dt]);
        }

        if (kt + 1 < nt) __syncthreads();      // next tile staged + all reads of cur done
        cur ^= 1;
    }

    // finalize: divide by l, write [4096][1024] (col = h*64+d)
    const int b = bh >> 4, h = bh & 15;
    #pragma unroll
    for (int j = 0; j < 4; ++j) {
        float inv = 1.f / lrow[j];
        int s = qw + lhi * 4 + j;
        size_t row = (size_t)(b * 2048 + s);
        #pragma unroll
        for (int dt = 0; dt < 4; ++dt) {
            int d = dt * 16 + llo;
            O[row * 1024 + h * 64 + d] = f2bs(o[dt][j] * inv);
        }
    }
}

// ---------------- in-place LayerNorm over rows of 1024 ----------------
__global__ __launch_bounds__(256) void ln_kernel(float* __restrict__ out,
        const float* __restrict__ gamma, const float* __restrict__ beta)
{
    const int row = blockIdx.x;
    float* p = out + (size_t)row * 1024;
    const int tid = threadIdx.x;
    float4 v = ((const float4*)p)[tid];
    float s = v.x + v.y + v.z + v.w;
    float ss = v.x * v.x + v.y * v.y + v.z * v.z + v.w * v.w;
    #pragma unroll
    for (int d = 1; d < 64; d <<= 1) {
        s  += __shfl_xor(s, d);
        ss += __shfl_xor(ss, d);
    }
    __shared__ float red[8];
    const int wave = tid >> 6, lane = tid & 63;
    if (lane == 0) { red[wave] = s; red[4 + wave] = ss; }
    __syncthreads();
    s  = red[0] + red[1] + red[2] + red[3];
    ss = red[4] + red[5] + red[6] + red[7];
    const float mu = s * (1.0f / 1024.0f);
    const float var = ss * (1.0f / 1024.0f) - mu * mu;
    const float rstd = rsqrtf(var + 1e-5f);
    float4 g = ((const float4*)gamma)[tid];
    float4 b = ((const float4*)beta)[tid];
    v.x = (v.x - mu) * rstd * g.x + b.x;
    v.y = (v.y - mu) * rstd * g.y + b.y;
    v.z = (v.z - mu) * rstd * g.z + b.z;
    v.w = (v.w - mu) * rstd * g.w + b.w;
    ((float4*)p)[tid] = v;
}

extern "C" void kernel_launch(void* const* d_in, const int* in_sizes, int n_in,
                              void* d_out, int out_size, void* d_ws, size_t ws_size,
                              hipStream_t stream)
{
    const float* x  = (const float*)d_in[0];
    const float* Wq = (const float*)d_in[1];
    const float* bq = (const float*)d_in[2];
    const float* Wk = (const float*)d_in[3];
    const float* bk = (const float*)d_in[4];
    const float* Wv = (const float*)d_in[5];
    const float* bv = (const float*)d_in[6];
    const float* Wo = (const float*)d_in[7];
    const float* bo = (const float*)d_in[8];
    const float* gamma = (const float*)d_in[9];
    const float* beta  = (const float*)d_in[10];
    float* out = (float*)d_out;

    char* ws = (char*)d_ws;
    short* xb   = (short*)(ws);                      // 8 MB; reused as ab
    short* wqkv = (short*)(ws + (8ull  << 20));      // 6 MB [3072][1024]
    short* wob  = (short*)(ws + (14ull << 20));      // 2 MB
    short* qb   = (short*)(ws + (16ull << 20));      // [2][16][2048][64] bf16
    short* kb   = (short*)(ws + (24ull << 20));      // [2][16][2048][64]
    short* vtb  = (short*)(ws + (32ull << 20));      // [2][16][64][2048]  (transposed!)
    short* ab   = xb;                                // attn out [4096][1024]

    cvt_kernel<<<4096, 256, 0, stream>>>(x,  xb, 1048576);
    cvt_kernel<<<1024, 256, 0, stream>>>(Wq, wqkv,           262144);
    cvt_kernel<<<1024, 256, 0, stream>>>(Wk, wqkv + 1048576, 262144);
    cvt_kernel<<<1024, 256, 0, stream>>>(Wv, wqkv + 2097152, 262144);
    cvt_kernel<<<1024, 256, 0, stream>>>(Wo, wob, 262144);

    gemm_bt<0><<<dim3(32, 24), 256, 0, stream>>>(xb, wqkv, 4096, 3072, 1024,
        bq, bk, bv, qb, kb, vtb, nullptr, nullptr, nullptr);

    attn_kernel<<<1024, 256, 0, stream>>>(qb, kb, vtb, ab);

    gemm_bt<1><<<dim3(32, 8), 256, 0, stream>>>(ab, wob, 4096, 1024, 1024,
        nullptr, nullptr, nullptr, nullptr, nullptr, nullptr, bo, x, out);

    ln_kernel<<<4096, 256, 0, stream>>>(out, gamma, beta);
}

// Round 3
// 161.318 us; speedup vs baseline: 1.9618x; 1.1668x over previous
//
#include <hip/hip_runtime.h>

typedef __attribute__((ext_vector_type(8))) short short8;
typedef __attribute__((ext_vector_type(4))) float f32x4;
typedef __attribute__((ext_vector_type(4))) short short4v;

__device__ __forceinline__ short f2bs(float f) {
    union { float f; unsigned u; } c; c.f = f;
    unsigned r = 0x7FFFu + ((c.u >> 16) & 1u);
    return (short)((c.u + r) >> 16);
}

__device__ __forceinline__ void gld_lds16(const void* g, void* l) {
    __builtin_amdgcn_global_load_lds(
        (const __attribute__((address_space(1))) unsigned int*)g,
        (__attribute__((address_space(3))) unsigned int*)l, 16, 0, 0);
}

__device__ __forceinline__ f32x4 mfma16(short8 a, short8 b, f32x4 c) {
    return __builtin_amdgcn_mfma_f32_16x16x32_bf16(a, b, c, 0, 0, 0);
}

// ---------------- conversion: fp32 -> bf16 (vectorized x4) ----------------
__global__ __launch_bounds__(256) void cvt_kernel(const float* __restrict__ src,
                                                  short* __restrict__ dst, int n4)
{
    int i = blockIdx.x * 256 + threadIdx.x;
    if (i >= n4) return;
    float4 v = ((const float4*)src)[i];
    short4v o;
    o.x = f2bs(v.x); o.y = f2bs(v.y); o.z = f2bs(v.z); o.w = f2bs(v.w);
    ((short4v*)dst)[i] = o;
}

// fused 4-weight conversion: Wq,Wk,Wv -> wqkv[3M]; Wo -> wob
__global__ __launch_bounds__(256) void cvtw_kernel(
    const float* __restrict__ Wq, const float* __restrict__ Wk,
    const float* __restrict__ Wv, const float* __restrict__ Wo,
    short* __restrict__ wqkv, short* __restrict__ wob)
{
    int i = blockIdx.x * 256 + threadIdx.x;      // 1M granules of 4
    int which = i >> 18, off = i & 262143;
    const float* src = which == 0 ? Wq : (which == 1 ? Wk : (which == 2 ? Wv : Wo));
    short* dst = which == 3 ? wob : (wqkv + (size_t)which * 1048576);
    float4 v = ((const float4*)src)[off];
    short4v o;
    o.x = f2bs(v.x); o.y = f2bs(v.y); o.z = f2bs(v.z); o.w = f2bs(v.w);
    ((short4v*)dst)[off] = o;
}

// ---------------- GEMM: C = A @ B^T (B stored [N][K] row-major) ----------------
// MODE 0: QKV — bias add; Q,K scatter to [b,h,s,d]; V scatter TRANSPOSED to [b,h,d,s].
// MODE 1: O-proj — + bo + residual x, write fp32.
#define BM 128
#define BN 128
#define BK 32

template<int MODE>
__global__ __launch_bounds__(256) void gemm_bt(
    const short* __restrict__ A, const short* __restrict__ B,
    int M, int N, int K,
    const float* __restrict__ b0, const float* __restrict__ b1, const float* __restrict__ b2,
    short* __restrict__ oq, short* __restrict__ ok_, short* __restrict__ ov,
    const float* __restrict__ bo, const float* __restrict__ xres,
    float* __restrict__ outf)
{
    __shared__ __align__(16) short As[BM * BK];
    __shared__ __align__(16) short Bs[BN * BK];
    const int tid = threadIdx.x;
    const int wave = tid >> 6, lane = tid & 63;
    const int lhi = lane >> 4, llo = lane & 15;
    const int row0 = blockIdx.x * BM, col0 = blockIdx.y * BN;
    const int wr = (wave >> 1) * 64, wc = (wave & 1) * 64;

    f32x4 acc[4][4] = {};

    const int c0 = tid, c1 = 256 + tid;
    const short* gA0 = A + (size_t)(row0 + (c0 >> 2)) * K + (c0 & 3) * 8;
    const short* gA1 = A + (size_t)(row0 + (c1 >> 2)) * K + (c1 & 3) * 8;
    const short* gB0 = B + (size_t)(col0 + (c0 >> 2)) * K + (c0 & 3) * 8;
    const short* gB1 = B + (size_t)(col0 + (c1 >> 2)) * K + (c1 & 3) * 8;
    short* lA0 = &As[(size_t)(wave * 64) * 8];
    short* lA1 = &As[(size_t)(256 + wave * 64) * 8];
    short* lB0 = &Bs[(size_t)(wave * 64) * 8];
    short* lB1 = &Bs[(size_t)(256 + wave * 64) * 8];

    for (int k0 = 0; k0 < K; k0 += BK) {
        gld_lds16(gA0 + k0, lA0);
        gld_lds16(gA1 + k0, lA1);
        gld_lds16(gB0 + k0, lB0);
        gld_lds16(gB1 + k0, lB1);
        __syncthreads();
        short8 af[4], bf[4];
        #pragma unroll
        for (int i = 0; i < 4; ++i) {
            af[i] = *(const short8*)&As[(wr + i * 16 + llo) * BK + lhi * 8];
            bf[i] = *(const short8*)&Bs[(wc + i * 16 + llo) * BK + lhi * 8];
        }
        #pragma unroll
        for (int i = 0; i < 4; ++i)
            #pragma unroll
            for (int j = 0; j < 4; ++j)
                acc[i][j] = mfma16(af[i], bf[j], acc[i][j]);
        __syncthreads();
    }

    // epilogue — C/D layout: col = lane&15, row = (lane>>4)*4 + reg
    #pragma unroll
    for (int i = 0; i < 4; ++i) {
        #pragma unroll
        for (int j = 0; j < 4; ++j) {
            #pragma unroll
            for (int r = 0; r < 4; ++r) {
                int m = row0 + wr + i * 16 + lhi * 4 + r;
                int n = col0 + wc + j * 16 + llo;
                float v = acc[i][j][r];
                if (MODE == 0) {
                    int which = n >> 10, nn = n & 1023;
                    const float* bia = which == 0 ? b0 : (which == 1 ? b1 : b2);
                    v += bia[nn];
                    int h = nn >> 6, d = nn & 63;
                    int bb = m >> 11, s = m & 2047;
                    short val = f2bs(v);
                    if (which == 2)
                        ov[((size_t)((bb * 16 + h) * 64 + d)) * 2048 + s] = val;
                    else {
                        short* dst = which == 0 ? oq : ok_;
                        dst[((size_t)((bb * 16 + h) * 2048 + s)) * 64 + d] = val;
                    }
                } else {
                    size_t idx = (size_t)m * N + n;
                    outf[idx] = v + bo[n] + xres[idx];
                }
            }
        }
    }
}

// ---------------- flash attention (causal), per (b,h) ----------------
// 4 waves x 16 q-rows; KV tile 64; swapped QK^T (S^T out) -> per-lane softmax.
#define SCL 0.18033688011f   /* (1/8) * log2(e) */

__global__ __launch_bounds__(256) void attn_kernel(
    const short* __restrict__ Q, const short* __restrict__ K,
    const short* __restrict__ Vt, short* __restrict__ O)
{
    const int id = blockIdx.x;                        // 1024 blocks
    const int bh = (id & 7) * 4 + (id >> 8);          // XCD-grouped bh
    const int qt = 31 - ((id >> 3) & 31);             // heavy q-tiles first
    const int q0 = qt * 64;

    const short* Qb = Q  + (size_t)bh * 2048 * 64;
    const short* Kb = K  + (size_t)bh * 2048 * 64;
    const short* Vb = Vt + (size_t)bh * 64 * 2048;

    __shared__ __align__(16) short Ks[2][64 * 64];
    __shared__ __align__(16) short Vs[2][64 * 64];
    __shared__ __align__(16) short Ps[4][16 * 68];

    const int tid = threadIdx.x, wave = tid >> 6, lane = tid & 63;
    const int lhi = lane >> 4, llo = lane & 15;
    const int qw = q0 + wave * 16;
    const int qg = qw + llo;                          // this lane's q row (softmax)

    // Q fragments (B operand now): lane holds Q[qw+llo][lhi*8..]
    const short8 qf0 = *(const short8*)&Qb[(size_t)(qw + llo) * 64 + lhi * 8];
    const short8 qf1 = *(const short8*)&Qb[(size_t)(qw + llo) * 64 + 32 + lhi * 8];

    // staging: linear LDS dest, pre-XOR-swizzled global source (involution)
    const int tr = tid >> 3, tc = tid & 7, sc = tc ^ (tr & 7);
    const short* kS0 = Kb + (size_t)tr * 64 + sc * 8;
    const short* kS1 = Kb + (size_t)(32 + tr) * 64 + sc * 8;
    const short* vS0 = Vb + (size_t)tr * 2048 + sc * 8;
    const short* vS1 = Vb + (size_t)(32 + tr) * 2048 + sc * 8;
    const int dOff = wave * 512;

    f32x4 o[4] = {};
    float mrow = -1e30f, lrow = 0.f;

    const int nt = q0 / 64 + 1;

    gld_lds16(kS0, Ks[0] + dOff);
    gld_lds16(kS1, Ks[0] + 2048 + dOff);
    gld_lds16(vS0, Vs[0] + dOff);
    gld_lds16(vS1, Vs[0] + 2048 + dOff);
    __syncthreads();

    const int swq = (llo & 7) << 3;                   // K/V row-XOR (row&7 == llo&7)
    int cur = 0;
    for (int kt = 0; kt < nt; ++kt) {
        const int kk0 = kt * 64;
        if (kt + 1 < nt) {
            const int nk = kk0 + 64;
            gld_lds16(kS0 + (size_t)nk * 64, Ks[cur ^ 1] + dOff);
            gld_lds16(kS1 + (size_t)nk * 64, Ks[cur ^ 1] + 2048 + dOff);
            gld_lds16(vS0 + nk, Vs[cur ^ 1] + dOff);
            gld_lds16(vS1 + nk, Vs[cur ^ 1] + 2048 + dOff);
        }

        // ---- S^T = K Q^T : st[t] holds k rows (lhi*4+j), q col (llo) ----
        f32x4 st[4];
        __builtin_amdgcn_s_setprio(1);
        #pragma unroll
        for (int t = 0; t < 4; ++t) {
            const int row = t * 16 + llo;
            short8 kf0 = *(const short8*)&Ks[cur][row * 64 + ((lhi * 8) ^ swq)];
            short8 kf1 = *(const short8*)&Ks[cur][row * 64 + ((lhi * 8 + 32) ^ swq)];
            f32x4 s = {};
            s = mfma16(kf0, qf0, s);
            s = mfma16(kf1, qf1, s);
            st[t][0] = s[0] * SCL; st[t][1] = s[1] * SCL;
            st[t][2] = s[2] * SCL; st[t][3] = s[3] * SCL;
        }
        __builtin_amdgcn_s_setprio(0);

        if (kt == nt - 1) {                           // diagonal: mask k > q
            #pragma unroll
            for (int t = 0; t < 4; ++t)
                #pragma unroll
                for (int j = 0; j < 4; ++j)
                    if (kk0 + t * 16 + lhi * 4 + j > qg) st[t][j] = -1e30f;
        }

        // ---- per-lane softmax: 15 in-reg max + 2 cross-lane hops ----
        float tmax = -1e30f;
        #pragma unroll
        for (int t = 0; t < 4; ++t)
            tmax = fmaxf(tmax, fmaxf(fmaxf(st[t][0], st[t][1]), fmaxf(st[t][2], st[t][3])));
        tmax = fmaxf(tmax, __shfl_xor(tmax, 16));
        tmax = fmaxf(tmax, __shfl_xor(tmax, 32));

        if (!__all(tmax - mrow <= 8.f)) {             // defer-max: rescale rarely
            const float mnew = fmaxf(mrow, tmax);
            const float al = exp2f(mrow - mnew);
            mrow = mnew;
            lrow *= al;
            #pragma unroll
            for (int j = 0; j < 4; ++j) {
                const float aj = __shfl(al, lhi * 4 + j);
                #pragma unroll
                for (int dt = 0; dt < 4; ++dt) o[dt][j] *= aj;
            }
        }

        // P = exp2(S - m); in-reg row sum + 2 hops; pack pairs to LDS
        float rs = 0.f;
        #pragma unroll
        for (int t = 0; t < 4; ++t)
            #pragma unroll
            for (int j = 0; j < 4; ++j) {
                st[t][j] = exp2f(st[t][j] - mrow);
                rs += st[t][j];
            }
        rs += __shfl_xor(rs, 16);
        rs += __shfl_xor(rs, 32);
        lrow += rs;

        int* Pw = (int*)Ps[wave];
        #pragma unroll
        for (int t = 0; t < 4; ++t)
            #pragma unroll
            for (int jj = 0; jj < 2; ++jj) {
                unsigned u = (unsigned short)f2bs(st[t][2 * jj]) |
                             ((unsigned)(unsigned short)f2bs(st[t][2 * jj + 1]) << 16);
                Pw[llo * 34 + t * 8 + lhi * 2 + jj] = u;
            }

        // ---- O += P V ----
        const short8 pf0 = *(const short8*)&Ps[wave][llo * 68 + lhi * 8];
        const short8 pf1 = *(const short8*)&Ps[wave][llo * 68 + 32 + lhi * 8];
        __builtin_amdgcn_s_setprio(1);
        #pragma unroll
        for (int dt = 0; dt < 4; ++dt) {
            const int row = dt * 16 + llo;
            short8 vf0 = *(const short8*)&Vs[cur][row * 64 + ((lhi * 8) ^ swq)];
            short8 vf1 = *(const short8*)&Vs[cur][row * 64 + ((lhi * 8 + 32) ^ swq)];
            o[dt] = mfma16(pf0, vf0, o[dt]);
            o[dt] = mfma16(pf1, vf1, o[dt]);
        }
        __builtin_amdgcn_s_setprio(0);

        if (kt + 1 < nt) __syncthreads();
        cur ^= 1;
    }

    // finalize: broadcast 1/l to o layout, write [4096][1024]
    const int b = bh >> 4, h = bh & 15;
    const float inv = 1.f / lrow;
    #pragma unroll
    for (int j = 0; j < 4; ++j) {
        const float ivj = __shfl(inv, lhi * 4 + j);
        int s = qw + lhi * 4 + j;
        size_t row = (size_t)(b * 2048 + s);
        #pragma unroll
        for (int dt = 0; dt < 4; ++dt) {
            int d = dt * 16 + llo;
            O[row * 1024 + h * 64 + d] = f2bs(o[dt][j] * ivj);
        }
    }
}

// ---------------- in-place LayerNorm over rows of 1024 ----------------
__global__ __launch_bounds__(256) void ln_kernel(float* __restrict__ out,
        const float* __restrict__ gamma, const float* __restrict__ beta)
{
    const int row = blockIdx.x;
    float* p = out + (size_t)row * 1024;
    const int tid = threadIdx.x;
    float4 v = ((const float4*)p)[tid];
    float s = v.x + v.y + v.z + v.w;
    float ss = v.x * v.x + v.y * v.y + v.z * v.z + v.w * v.w;
    #pragma unroll
    for (int d = 1; d < 64; d <<= 1) {
        s  += __shfl_xor(s, d);
        ss += __shfl_xor(ss, d);
    }
    __shared__ float red[8];
    const int wave = tid >> 6, lane = tid & 63;
    if (lane == 0) { red[wave] = s; red[4 + wave] = ss; }
    __syncthreads();
    s  = red[0] + red[1] + red[2] + red[3];
    ss = red[4] + red[5] + red[6] + red[7];
    const float mu = s * (1.0f / 1024.0f);
    const float var = ss * (1.0f / 1024.0f) - mu * mu;
    const float rstd = rsqrtf(var + 1e-5f);
    float4 g = ((const float4*)gamma)[tid];
    float4 b = ((const float4*)beta)[tid];
    v.x = (v.x - mu) * rstd * g.x + b.x;
    v.y = (v.y - mu) * rstd * g.y + b.y;
    v.z = (v.z - mu) * rstd * g.z + b.z;
    v.w = (v.w - mu) * rstd * g.w + b.w;
    ((float4*)p)[tid] = v;
}

extern "C" void kernel_launch(void* const* d_in, const int* in_sizes, int n_in,
                              void* d_out, int out_size, void* d_ws, size_t ws_size,
                              hipStream_t stream)
{
    const float* x  = (const float*)d_in[0];
    const float* Wq = (const float*)d_in[1];
    const float* bq = (const float*)d_in[2];
    const float* Wk = (const float*)d_in[3];
    const float* bk = (const float*)d_in[4];
    const float* Wv = (const float*)d_in[5];
    const float* bv = (const float*)d_in[6];
    const float* Wo = (const float*)d_in[7];
    const float* bo = (const float*)d_in[8];
    const float* gamma = (const float*)d_in[9];
    const float* beta  = (const float*)d_in[10];
    float* out = (float*)d_out;

    char* ws = (char*)d_ws;
    short* xb   = (short*)(ws);                      // 8 MB; reused as ab
    short* wqkv = (short*)(ws + (8ull  << 20));      // 6 MB [3072][1024]
    short* wob  = (short*)(ws + (14ull << 20));      // 2 MB
    short* qb   = (short*)(ws + (16ull << 20));      // [2][16][2048][64] bf16
    short* kb   = (short*)(ws + (24ull << 20));      // [2][16][2048][64]
    short* vtb  = (short*)(ws + (32ull << 20));      // [2][16][64][2048]  (transposed)
    short* ab   = xb;                                // attn out [4096][1024]

    cvt_kernel<<<4096, 256, 0, stream>>>(x, xb, 1048576);
    cvtw_kernel<<<4096, 256, 0, stream>>>(Wq, Wk, Wv, Wo, wqkv, wob);

    gemm_bt<0><<<dim3(32, 24), 256, 0, stream>>>(xb, wqkv, 4096, 3072, 1024,
        bq, bk, bv, qb, kb, vtb, nullptr, nullptr, nullptr);

    attn_kernel<<<1024, 256, 0, stream>>>(qb, kb, vtb, ab);

    gemm_bt<1><<<dim3(32, 8), 256, 0, stream>>>(ab, wob, 4096, 1024, 1024,
        nullptr, nullptr, nullptr, nullptr, nullptr, nullptr, bo, x, out);

    ln_kernel<<<4096, 256, 0, stream>>>(out, gamma, beta);
}